// Round 8
// baseline (3488.851 us; speedup 1.0000x reference)
//
#include <hip/hip_runtime.h>

typedef __attribute__((ext_vector_type(8))) short bf16x8;
typedef __attribute__((ext_vector_type(4))) float f32x4;
typedef __attribute__((ext_vector_type(2))) float f32x2;
typedef __attribute__((ext_vector_type(4))) unsigned int u32x4;
typedef __attribute__((ext_vector_type(2))) unsigned int u32x2;

#define DEV static __device__ __forceinline__

DEV unsigned short f2bf(float x){
  unsigned u = __float_as_uint(x);
  u += 0x7fffu + ((u >> 16) & 1u);
  return (unsigned short)(u >> 16);
}
DEV float bf2f(unsigned short b){ return __uint_as_float(((unsigned)b) << 16); }

// legacy 128-tile swizzle (8 granules per 128B row)
DEV int swz8(int row){ return (row + (row >> 3)) & 7; }
DEV int swzb(int row, int cb){ return cb ^ (swz8(row) << 4); }
DEV int loff(int row, int cb){ return row * 128 + swzb(row, cb); }

DEV f32x4 mfma16(bf16x8 a, bf16x8 b, f32x4 c){
  return __builtin_amdgcn_mfma_f32_16x16x32_bf16(a, b, c, 0, 0, 0);
}

typedef __attribute__((address_space(3))) void lds_vt;
typedef const __attribute__((address_space(1))) void gm_vt;
DEV void gload16(const void* g, void* l){
  __builtin_amdgcn_global_load_lds((gm_vt*)g, (lds_vt*)l, 16, 0, 0);
}

// ============== BIG-TILE PIPELINED GEMM (256x256, BK=32, bf16 planes) ==============
// 512 thr / 8 waves (2x4); wave tile 128x64; M_rep=8, N_rep=4.
// LDS 64KB: 2 buf x (A 16KB + B 16KB) -> 2 blocks/CU (4 waves/SIMD, independent
// barriers -> cross-block MFMA/ds_read/stage overlap). global_load_lds staging,
// inverse-swizzled global source (linear LDS dest), swizzled ds_read_b128.
// 4-granule swizzle: g ^= (row>>1)&3 (2-way b128 aliasing = free).
// Per tile t: vmcnt(0) [drains stage(t), issued one tile ago]; s_barrier;
// issue stage(t+1) into buffer freed by compute(t-1); 12 ds_reads; 32 MFMA.
// NPAIR=3: virtual K*3 plane-pair sequence for the hi/lo split-3 product.
// EPI: 0 = f32 C store; 1 = +bias, split-bf16 store to oh/ol.

template<int NPAIR, int EPI>
__global__ __launch_bounds__(512, 4) void gemm_big(
    const unsigned short* __restrict__ A0p, const unsigned short* __restrict__ A1p,
    const unsigned short* __restrict__ B0p, const unsigned short* __restrict__ B1p,
    int lda, int ldb, int MBLK, int NBLK, int nkt,
    size_t a_bs, size_t b_bs,
    float* __restrict__ C, int ldc, size_t c_bs,
    const float* __restrict__ bias,
    unsigned short* __restrict__ oh, unsigned short* __restrict__ ol)
{
  __shared__ char lds[65536];
  const int tid  = threadIdx.x;
  const int w    = tid >> 6;
  const int lane = tid & 63;
  const int wr = w >> 2, wc = w & 3;
  const int lr = lane & 15, lg = lane >> 4;

  // chunked XCD swizzle (nwg % 8 == 0)
  const int nwg = gridDim.x;
  const int wg  = (blockIdx.x & 7) * (nwg >> 3) + (blockIdx.x >> 3);
  const int per = MBLK * NBLK;
  const int b   = wg / per;
  const int rr  = wg - b * per;
  const int m0  = (rr / NBLK) * 256;
  const int n0  = (rr % NBLK) * 256;

  const unsigned short* Ab0 = A0p + b * a_bs + (size_t)m0 * lda;
  const unsigned short* Ab1 = A1p + b * a_bs + (size_t)m0 * lda;
  const unsigned short* Bb0 = B0p + b * b_bs + (size_t)n0 * ldb;
  const unsigned short* Bb1 = B1p + b * b_bs + (size_t)n0 * ldb;

  const int NT = nkt * NPAIR;
  const int wu = __builtin_amdgcn_readfirstlane(w);

  f32x4 acc[8][4];
#pragma unroll
  for (int m = 0; m < 8; ++m)
#pragma unroll
    for (int n = 0; n < 4; ++n) acc[m][n] = (f32x4){0.f, 0.f, 0.f, 0.f};

  auto STAGE = [&](int t, int bufsel){
    int kp, pr;
    if (NPAIR == 3){ kp = t / 3; pr = t - kp * 3; } else { kp = t; pr = 0; }
    const unsigned short* Ap = ((NPAIR == 3) && pr == 1) ? Ab1 : Ab0;
    const unsigned short* Bp = ((NPAIR == 3) && pr == 2) ? Bb1 : Bb0;
    Ap += kp * 32; Bp += kp * 32;
    char* Abuf = lds + bufsel * 32768;
    char* Bbuf = Abuf + 16384;
#pragma unroll
    for (int j = 0; j < 2; ++j){
      int rbase = wu * 32 + j * 16;
      int row = rbase + (lane >> 2);
      int g = (lane & 3) ^ ((row >> 1) & 3);
      gload16(Ap + (size_t)row * lda + g * 8, Abuf + rbase * 64);
      gload16(Bp + (size_t)row * ldb + g * 8, Bbuf + rbase * 64);
    }
  };

  STAGE(0, 0);

  for (int t = 0; t < NT; ++t){
    asm volatile("s_waitcnt vmcnt(0)" ::: "memory");
    __builtin_amdgcn_s_barrier();
    __builtin_amdgcn_sched_barrier(0);
    if (t + 1 < NT) STAGE(t + 1, (t + 1) & 1);
    __builtin_amdgcn_sched_barrier(0);

    const char* Abuf = lds + (t & 1) * 32768;
    const char* Bbuf = Abuf + 16384;
    bf16x8 afr[8], bfr[4];
#pragma unroll
    for (int n = 0; n < 4; ++n){
      int row = wc * 64 + n * 16 + lr;
      int g = lg ^ ((row >> 1) & 3);
      bfr[n] = *(const bf16x8*)(Bbuf + row * 64 + g * 16);
    }
#pragma unroll
    for (int m = 0; m < 8; ++m){
      int row = wr * 128 + m * 16 + lr;
      int g = lg ^ ((row >> 1) & 3);
      afr[m] = *(const bf16x8*)(Abuf + row * 64 + g * 16);
    }
    __builtin_amdgcn_s_setprio(1);
#pragma unroll
    for (int m = 0; m < 8; ++m)
#pragma unroll
      for (int n = 0; n < 4; ++n)
        acc[m][n] = mfma16(afr[m], bfr[n], acc[m][n]);
    __builtin_amdgcn_s_setprio(0);
  }

#pragma unroll
  for (int m = 0; m < 8; ++m){
    int grow = m0 + wr * 128 + m * 16 + lg * 4;
#pragma unroll
    for (int n = 0; n < 4; ++n){
      int gcol = n0 + wc * 64 + n * 16 + lr;
      if (EPI == 0){
#pragma unroll
        for (int j = 0; j < 4; ++j)
          C[b * c_bs + (size_t)(grow + j) * ldc + gcol] = acc[m][n][j];
      } else {
        float bv = bias[gcol];
#pragma unroll
        for (int j = 0; j < 4; ++j){
          float v = acc[m][n][j] + bv;
          unsigned short h = f2bf(v);
          size_t idx = (size_t)(grow + j) * ldc + gcol;
          oh[idx] = h;
          ol[idx] = f2bf(v - bf2f(h));
        }
      }
    }
  }
}

// ---------------- legacy staging / compute (fallback tiers) ----------------

DEV void stage_raw(char* L, const unsigned short* src, int lda, int tid){
#pragma unroll
  for (int i = 0; i < 4; ++i){
    int chunk = i * 256 + tid;
    int row = chunk >> 3;
    int c8 = (chunk & 7) << 3;
    u32x4 v = *(const u32x4*)(src + (size_t)row * lda + c8);
    *(u32x4*)(L + row * 128 + swzb(row, c8 << 1)) = v;
  }
}

DEV void stage_f32_split(char* Lhi, char* Llo, const float* src, int lda, int tid){
#pragma unroll
  for (int i = 0; i < 8; ++i){
    int chunk = i * 256 + tid;
    int row = chunk >> 4;
    int c4 = (chunk & 15) << 2;
    f32x4 v = *(const f32x4*)(src + (size_t)row * lda + c4);
    unsigned short h0 = f2bf(v[0]), h1 = f2bf(v[1]), h2 = f2bf(v[2]), h3 = f2bf(v[3]);
    u32x2 hw, lw;
    hw[0] = (unsigned)h0 | ((unsigned)h1 << 16); hw[1] = (unsigned)h2 | ((unsigned)h3 << 16);
    lw[0] = (unsigned)f2bf(v[0] - bf2f(h0)) | ((unsigned)f2bf(v[1] - bf2f(h1)) << 16);
    lw[1] = (unsigned)f2bf(v[2] - bf2f(h2)) | ((unsigned)f2bf(v[3] - bf2f(h3)) << 16);
    int off = row * 128 + swzb(row, c4 << 1);
    *(u32x2*)(Lhi + off) = hw;
    *(u32x2*)(Llo + off) = lw;
  }
}

DEV void stage_f32_plain(char* L, const float* src, int lda, int tid){
#pragma unroll
  for (int i = 0; i < 8; ++i){
    int chunk = i * 256 + tid;
    int row = chunk >> 4;
    int c4 = (chunk & 15) << 2;
    f32x4 v = *(const f32x4*)(src + (size_t)row * lda + c4);
    u32x2 hw;
    hw[0] = (unsigned)f2bf(v[0]) | ((unsigned)f2bf(v[1]) << 16);
    hw[1] = (unsigned)f2bf(v[2]) | ((unsigned)f2bf(v[3]) << 16);
    *(u32x2*)(L + row * 128 + swzb(row, c4 << 1)) = hw;
  }
}

DEV void stage_f32_T(char* L, const float* src, int ldb, int tid){
#pragma unroll
  for (int i = 0; i < 8; ++i){
    int mb = i * 256 + tid;
    int np = mb & 63, kp = mb >> 6;
    int gk = kp << 1, gn = np << 1;
    const float* p = src + (size_t)gk * ldb + gn;
    f32x2 r0 = *(const f32x2*)p;
    f32x2 r1 = *(const f32x2*)(p + ldb);
    *(unsigned*)(L + gn * 128 + swzb(gn, gk << 1))           = (unsigned)f2bf(r0[0]) | ((unsigned)f2bf(r1[0]) << 16);
    *(unsigned*)(L + (gn + 1) * 128 + swzb(gn + 1, gk << 1)) = (unsigned)f2bf(r0[1]) | ((unsigned)f2bf(r1[1]) << 16);
  }
}

DEV void compute_split(f32x4 acc[4][4], const char* Ahi, const char* Alo,
                       const char* Bhi, const char* Blo, int wr, int wc, int lane){
  int lr = lane & 15, lg = lane >> 4;
#pragma unroll
  for (int kk = 0; kk < 2; ++kk){
    int cb = kk * 64 + lg * 16;
    bf16x8 ah[4], al[4], bh[4], bl[4];
#pragma unroll
    for (int m = 0; m < 4; ++m){
      int r = wr * 64 + m * 16 + lr;
      ah[m] = *(const bf16x8*)(Ahi + loff(r, cb));
      al[m] = *(const bf16x8*)(Alo + loff(r, cb));
    }
#pragma unroll
    for (int n = 0; n < 4; ++n){
      int r = wc * 64 + n * 16 + lr;
      bh[n] = *(const bf16x8*)(Bhi + loff(r, cb));
      bl[n] = *(const bf16x8*)(Blo + loff(r, cb));
    }
#pragma unroll
    for (int m = 0; m < 4; ++m)
#pragma unroll
      for (int n = 0; n < 4; ++n){
        acc[m][n] = mfma16(ah[m], bh[n], acc[m][n]);
        acc[m][n] = mfma16(al[m], bh[n], acc[m][n]);
        acc[m][n] = mfma16(ah[m], bl[n], acc[m][n]);
      }
  }
}

DEV void compute_plain(f32x4 acc[4][4], const char* A, const char* B, int wr, int wc, int lane){
  int lr = lane & 15, lg = lane >> 4;
#pragma unroll
  for (int kk = 0; kk < 2; ++kk){
    int cb = kk * 64 + lg * 16;
    bf16x8 af[4], bf_[4];
#pragma unroll
    for (int m = 0; m < 4; ++m)
      af[m] = *(const bf16x8*)(A + loff(wr * 64 + m * 16 + lr, cb));
#pragma unroll
    for (int n = 0; n < 4; ++n)
      bf_[n] = *(const bf16x8*)(B + loff(wc * 64 + n * 16 + lr, cb));
#pragma unroll
    for (int m = 0; m < 4; ++m)
#pragma unroll
      for (int n = 0; n < 4; ++n)
        acc[m][n] = mfma16(af[m], bf_[n], acc[m][n]);
  }
}

// ---------------- prep kernels ----------------

template<bool SPLIT>
__global__ __launch_bounds__(256) void transpose_prep(
    const float* __restrict__ in, size_t in_bstride, int in_ld,
    unsigned short* __restrict__ oh, unsigned short* __restrict__ ol,
    size_t out_bstride, int out_ld)
{
  __shared__ float T[64][65];
  const int t = threadIdx.x;
  const int r0 = blockIdx.x * 64, c0 = blockIdx.y * 64;
  const float* src = in + (size_t)blockIdx.z * in_bstride;
#pragma unroll
  for (int i = 0; i < 4; ++i){
    int r = (t >> 4) + i * 16;
    int c = (t & 15) * 4;
    f32x4 v = *(const f32x4*)(src + (size_t)(r0 + r) * in_ld + c0 + c);
#pragma unroll
    for (int j = 0; j < 4; ++j) T[r][c + j] = v[j];
  }
  __syncthreads();
#pragma unroll
  for (int i = 0; i < 4; ++i){
    int c = (t >> 4) + i * 16;
    int r = (t & 15) * 4;
    float v0 = T[r][c], v1 = T[r + 1][c], v2 = T[r + 2][c], v3 = T[r + 3][c];
    unsigned short h0 = f2bf(v0), h1 = f2bf(v1), h2 = f2bf(v2), h3 = f2bf(v3);
    u32x2 hw;
    hw[0] = (unsigned)h0 | ((unsigned)h1 << 16);
    hw[1] = (unsigned)h2 | ((unsigned)h3 << 16);
    size_t off = (size_t)blockIdx.z * out_bstride + (size_t)(c0 + c) * out_ld + r0 + r;
    *(u32x2*)(oh + off) = hw;
    if (SPLIT){
      u32x2 lw;
      lw[0] = (unsigned)f2bf(v0 - bf2f(h0)) | ((unsigned)f2bf(v1 - bf2f(h1)) << 16);
      lw[1] = (unsigned)f2bf(v2 - bf2f(h2)) | ((unsigned)f2bf(v3 - bf2f(h3)) << 16);
      *(u32x2*)(ol + off) = lw;
    }
  }
}

__global__ __launch_bounds__(256) void split_prep(
    const float* __restrict__ in, unsigned short* __restrict__ oh,
    unsigned short* __restrict__ ol)
{
  size_t i = ((size_t)blockIdx.x * 256 + threadIdx.x) * 4;
  f32x4 v = *(const f32x4*)(in + i);
  unsigned short h0 = f2bf(v[0]), h1 = f2bf(v[1]), h2 = f2bf(v[2]), h3 = f2bf(v[3]);
  u32x2 hw, lw;
  hw[0] = (unsigned)h0 | ((unsigned)h1 << 16); hw[1] = (unsigned)h2 | ((unsigned)h3 << 16);
  lw[0] = (unsigned)f2bf(v[0] - bf2f(h0)) | ((unsigned)f2bf(v[1] - bf2f(h1)) << 16);
  lw[1] = (unsigned)f2bf(v[2] - bf2f(h2)) | ((unsigned)f2bf(v[3] - bf2f(h3)) << 16);
  *(u32x2*)(oh + i) = hw;
  *(u32x2*)(ol + i) = lw;
}

// ---------------- legacy kernels (fallback tiers) ----------------

__global__ __launch_bounds__(256, 2) void keys_gemm(
    const float* __restrict__ enc,
    const unsigned short* __restrict__ WaTh, const unsigned short* __restrict__ WaTl,
    const float* __restrict__ bias,
    unsigned short* __restrict__ khi, unsigned short* __restrict__ klo)
{
  __shared__ char lds[65536];
  char *Ahi = lds, *Alo = lds + 16384, *Bhi = lds + 32768, *Blo = lds + 49152;
  const int tid = threadIdx.x;
  const int lane = tid & 63, w = tid >> 6;
  const int wr = w >> 1, wc = w & 1;
  const int lr = lane & 15, lg = lane >> 4;
  const int m0 = blockIdx.y * 128;
  const int n0 = blockIdx.x * 128;

  f32x4 acc[4][4];
#pragma unroll
  for (int m = 0; m < 4; ++m)
#pragma unroll
    for (int n = 0; n < 4; ++n) acc[m][n] = (f32x4){0.f, 0.f, 0.f, 0.f};

  for (int k0 = 0; k0 < 1024; k0 += 64){
    __syncthreads();
    stage_f32_split(Ahi, Alo, enc + (size_t)m0 * 1024 + k0, 1024, tid);
    stage_raw(Bhi, WaTh + (size_t)n0 * 1024 + k0, 1024, tid);
    stage_raw(Blo, WaTl + (size_t)n0 * 1024 + k0, 1024, tid);
    __syncthreads();
    compute_split(acc, Ahi, Alo, Bhi, Blo, wr, wc, lane);
  }

#pragma unroll
  for (int n = 0; n < 4; ++n){
    int col = n0 + wc * 64 + n * 16 + lr;
    float bv = bias[col];
#pragma unroll
    for (int m = 0; m < 4; ++m){
      int rbase = m0 + wr * 64 + m * 16 + lg * 4;
#pragma unroll
      for (int j = 0; j < 4; ++j){
        float v = acc[m][n][j] + bv;
        unsigned short h = f2bf(v);
        size_t idx = (size_t)(rbase + j) * 1024 + col;
        khi[idx] = h;
        klo[idx] = f2bf(v - bf2f(h));
      }
    }
  }
}

template<bool PRESPLIT>
__global__ __launch_bounds__(256, 2) void score_gemm(
    const float* __restrict__ dec,
    const unsigned short* __restrict__ dech, const unsigned short* __restrict__ decl,
    const unsigned short* __restrict__ khi, const unsigned short* __restrict__ klo,
    float* __restrict__ scores)
{
  __shared__ char lds[65536];
  char *Ahi = lds, *Alo = lds + 16384, *Bhi = lds + 32768, *Blo = lds + 49152;
  const int tid = threadIdx.x;
  const int lane = tid & 63, w = tid >> 6;
  const int wr = w >> 1, wc = w & 1;
  const int lr = lane & 15, lg = lane >> 4;
  const int b  = blockIdx.z;
  const int m0 = blockIdx.y * 128;
  const int n0 = blockIdx.x * 128;

  f32x4 acc[4][4];
#pragma unroll
  for (int m = 0; m < 4; ++m)
#pragma unroll
    for (int n = 0; n < 4; ++n) acc[m][n] = (f32x4){0.f, 0.f, 0.f, 0.f};

  const size_t arow = (size_t)b * 2048 + m0;
  const size_t brow = (size_t)b * 2048 + n0;

  for (int k0 = 0; k0 < 1024; k0 += 64){
    __syncthreads();
    if (PRESPLIT){
      stage_raw(Ahi, dech + arow * 1024 + k0, 1024, tid);
      stage_raw(Alo, decl + arow * 1024 + k0, 1024, tid);
    } else {
      stage_f32_split(Ahi, Alo, dec + arow * 1024 + k0, 1024, tid);
    }
    stage_raw(Bhi, khi + brow * 1024 + k0, 1024, tid);
    stage_raw(Blo, klo + brow * 1024 + k0, 1024, tid);
    __syncthreads();
    compute_split(acc, Ahi, Alo, Bhi, Blo, wr, wc, lane);
  }

#pragma unroll
  for (int n = 0; n < 4; ++n){
    int col = n0 + wc * 64 + n * 16 + lr;
#pragma unroll
    for (int m = 0; m < 4; ++m){
      int rbase = m0 + wr * 64 + m * 16 + lg * 4;
#pragma unroll
      for (int j = 0; j < 4; ++j)
        scores[((size_t)b * 2048 + rbase + j) * 2048 + col] = acc[m][n][j];
    }
  }
}

// ---------------- softmax ----------------

template<bool DUALW>
__global__ __launch_bounds__(256, 4) void softmax_k(float* scores, unsigned short* alignb)
{
  const int row = blockIdx.x;
  const int t = threadIdx.x;
  float* src = scores + (size_t)row * 2048;
  f32x4 va = *(const f32x4*)(src + t * 8);
  f32x4 vb = *(const f32x4*)(src + t * 8 + 4);
  float f[8];
#pragma unroll
  for (int j = 0; j < 4; ++j){ f[j] = va[j]; f[4 + j] = vb[j]; }
  float m = -3.0e38f;
#pragma unroll
  for (int j = 0; j < 8; ++j) m = fmaxf(m, f[j]);
#pragma unroll
  for (int o = 1; o < 64; o <<= 1) m = fmaxf(m, __shfl_xor(m, o));
  __shared__ float red[4];
  const int wid = t >> 6;
  if ((t & 63) == 0) red[wid] = m;
  __syncthreads();
  m = fmaxf(fmaxf(red[0], red[1]), fmaxf(red[2], red[3]));
  float p[8]; float s = 0.f;
#pragma unroll
  for (int j = 0; j < 8; ++j){ p[j] = __expf(f[j] - m); s += p[j]; }
#pragma unroll
  for (int o = 1; o < 64; o <<= 1) s += __shfl_xor(s, o);
  __syncthreads();
  if ((t & 63) == 0) red[wid] = s;
  __syncthreads();
  s = (red[0] + red[1]) + (red[2] + red[3]);
  float inv = 1.0f / s;
  f32x4 oa, ob;
#pragma unroll
  for (int j = 0; j < 4; ++j){ oa[j] = p[j] * inv; ob[j] = p[4 + j] * inv; }
  *(f32x4*)(src + t * 8)     = oa;
  *(f32x4*)(src + t * 8 + 4) = ob;
  if (DUALW){
    u32x4 wv;
#pragma unroll
    for (int j = 0; j < 4; ++j){
      float x0 = (j < 2) ? oa[2 * j] : ob[2 * j - 4];
      float x1 = (j < 2) ? oa[2 * j + 1] : ob[2 * j - 3];
      wv[j] = (unsigned)f2bf(x0) | ((unsigned)f2bf(x1) << 16);
    }
    *(u32x4*)(alignb + (size_t)row * 2048 + t * 8) = wv;
  }
}

// ---------------- legacy ctx kernels (fallback tiers) ----------------

__global__ __launch_bounds__(256, 3) void ctx_gemm_fast(
    const unsigned short* __restrict__ alignb,
    const unsigned short* __restrict__ encT,
    float* __restrict__ ctx)
{
  __shared__ char lds[32768];
  char *A = lds, *B = lds + 16384;
  const int tid = threadIdx.x;
  const int lane = tid & 63, w = tid >> 6;
  const int wr = w >> 1, wc = w & 1;
  const int lr = lane & 15, lg = lane >> 4;
  const int wg = blockIdx.x;
  const int n0 = (wg & 7) * 128;
  const int m0 = ((wg >> 3) & 15) * 128;
  const int b  = wg >> 7;

  const unsigned short* Asrc = alignb + ((size_t)b * 2048 + m0) * 2048;
  const unsigned short* Bsrc = encT   + (size_t)b * 2097152 + (size_t)n0 * 2048;

  f32x4 acc[4][4];
#pragma unroll
  for (int m = 0; m < 4; ++m)
#pragma unroll
    for (int n = 0; n < 4; ++n) acc[m][n] = (f32x4){0.f, 0.f, 0.f, 0.f};

  const int row_ = tid >> 3;
  const int c8_  = (tid & 7) << 3;

  u32x4 ra[4], rb[4];
#pragma unroll
  for (int i = 0; i < 4; ++i){
    int row = row_ + i * 32;
    ra[i] = *(const u32x4*)(Asrc + (size_t)row * 2048 + c8_);
    rb[i] = *(const u32x4*)(Bsrc + (size_t)row * 2048 + c8_);
  }

  for (int t = 0; t < 32; ++t){
    __syncthreads();
#pragma unroll
    for (int i = 0; i < 4; ++i){
      int row = row_ + i * 32;
      int off = row * 128 + swzb(row, c8_ << 1);
      *(u32x4*)(A + off) = ra[i];
      *(u32x4*)(B + off) = rb[i];
    }
    __syncthreads();
    if (t + 1 < 32){
      int k0 = (t + 1) * 64;
#pragma unroll
      for (int i = 0; i < 4; ++i){
        int row = row_ + i * 32;
        ra[i] = *(const u32x4*)(Asrc + (size_t)row * 2048 + k0 + c8_);
        rb[i] = *(const u32x4*)(Bsrc + (size_t)row * 2048 + k0 + c8_);
      }
    }
    compute_plain(acc, A, B, wr, wc, lane);
  }

#pragma unroll
  for (int n = 0; n < 4; ++n){
    int col = n0 + wc * 64 + n * 16 + lr;
#pragma unroll
    for (int m = 0; m < 4; ++m){
      int rbase = m0 + wr * 64 + m * 16 + lg * 4;
#pragma unroll
      for (int j = 0; j < 4; ++j)
        ctx[((size_t)b * 2048 + rbase + j) * 1024 + col] = acc[m][n][j];
    }
  }
}

template<bool TRANS_WS>
__global__ __launch_bounds__(256, 2) void ctx_gemm(
    const float* __restrict__ alignf,
    const float* __restrict__ enc, const unsigned short* __restrict__ encT,
    float* __restrict__ ctx)
{
  __shared__ char lds[32768];
  char *A = lds, *B = lds + 16384;
  const int tid = threadIdx.x;
  const int lane = tid & 63, w = tid >> 6;
  const int wr = w >> 1, wc = w & 1;
  const int lr = lane & 15, lg = lane >> 4;
  const int b  = blockIdx.z;
  const int m0 = blockIdx.y * 128;
  const int n0 = blockIdx.x * 128;

  f32x4 acc[4][4];
#pragma unroll
  for (int m = 0; m < 4; ++m)
#pragma unroll
    for (int n = 0; n < 4; ++n) acc[m][n] = (f32x4){0.f, 0.f, 0.f, 0.f};

  const float* Asrc = alignf + ((size_t)b * 2048 + m0) * 2048;

  for (int k0 = 0; k0 < 2048; k0 += 64){
    __syncthreads();
    stage_f32_plain(A, Asrc + k0, 2048, tid);
    if (TRANS_WS)
      stage_raw(B, encT + (size_t)b * 2097152 + (size_t)n0 * 2048 + k0, 2048, tid);
    else
      stage_f32_T(B, enc + ((size_t)b * 2048 + k0) * 1024 + n0, 1024, tid);
    __syncthreads();
    compute_plain(acc, A, B, wr, wc, lane);
  }

#pragma unroll
  for (int n = 0; n < 4; ++n){
    int col = n0 + wc * 64 + n * 16 + lr;
#pragma unroll
    for (int m = 0; m < 4; ++m){
      int rbase = m0 + wr * 64 + m * 16 + lg * 4;
#pragma unroll
      for (int j = 0; j < 4; ++j)
        ctx[((size_t)b * 2048 + rbase + j) * 1024 + col] = acc[m][n][j];
    }
  }
}

// ---------------- launch ----------------
// d_out (f32): ctx [8,2048,1024] | align [8,2048,2048].
// keys bf16 hi/lo planes in ctx region (67 MB, overwritten last).
// Wa^T planes in align tail (4 MB). enc hi/lo planes in align head (67 MB) —
// both consumed by keys stage, then overwritten by score output (stream order).
// d_ws tiers: >=33.5 MB encT | >=100.7 MB +alignb | >=167.8 MB +dec planes.

extern "C" void kernel_launch(void* const* d_in, const int* in_sizes, int n_in,
                              void* d_out, int out_size, void* d_ws, size_t ws_size,
                              hipStream_t stream) {
  const float* enc  = (const float*)d_in[0];
  const float* dec  = (const float*)d_in[1];
  const float* Wa   = (const float*)d_in[2];
  const float* bias = (const float*)d_in[3];

  float* out    = (float*)d_out;
  float* ctx    = out;
  float* alignf = out + (size_t)8 * 2048 * 1024;
  float* scores = alignf;

  unsigned short* khi = (unsigned short*)ctx;
  unsigned short* klo = khi + (size_t)16384 * 1024;

  unsigned short* WaTh = (unsigned short*)(alignf + 32505856);
  unsigned short* WaTl = WaTh + (size_t)1024 * 1024;

  // enc hi/lo planes parked at the head of the align region (bytes 0..67MB)
  unsigned short* ench = (unsigned short*)alignf;
  unsigned short* encl = ench + (size_t)16384 * 1024;

  const size_t ENCT_B   = (size_t)8 * 1024 * 2048 * 2;
  const size_t ALIGNB_B = (size_t)8 * 2048 * 2048 * 2;
  const size_t DECP_B   = (size_t)8 * 2048 * 1024 * 2;
  bool has_encT   = ws_size >= ENCT_B;
  bool has_alignb = ws_size >= ENCT_B + ALIGNB_B;
  bool has_decp   = ws_size >= ENCT_B + ALIGNB_B + 2 * DECP_B;
  unsigned short* encT   = (unsigned short*)d_ws;
  unsigned short* alignb = (unsigned short*)((char*)d_ws + ENCT_B);
  unsigned short* dech   = (unsigned short*)((char*)d_ws + ENCT_B + ALIGNB_B);
  unsigned short* decl   = (unsigned short*)((char*)d_ws + ENCT_B + ALIGNB_B + DECP_B);

  transpose_prep<true><<<dim3(16, 16, 1), 256, 0, stream>>>(
      Wa, 0, 1024, WaTh, WaTl, 0, 1024);
  if (has_encT)
    transpose_prep<false><<<dim3(32, 16, 8), 256, 0, stream>>>(
        enc, (size_t)2048 * 1024, 1024, encT, nullptr, (size_t)1024 * 2048, 2048);
  if (has_decp)
    split_prep<<<dim3(16384), 256, 0, stream>>>(dec, dech, decl);

  if (has_decp){
    // big-tile path for all three GEMMs
    split_prep<<<dim3(16384), 256, 0, stream>>>(enc, ench, encl);
    gemm_big<3, 1><<<256, 512, 0, stream>>>(
        ench, encl, WaTh, WaTl, 1024, 1024, 64, 4, 32,
        0, 0, nullptr, 1024, 0, bias, khi, klo);
    gemm_big<3, 0><<<512, 512, 0, stream>>>(
        dech, decl, khi, klo, 1024, 1024, 8, 8, 32,
        (size_t)2048 * 1024, (size_t)2048 * 1024, scores, 2048, (size_t)2048 * 2048,
        nullptr, nullptr, nullptr);
    softmax_k<true><<<dim3(16384), 256, 0, stream>>>(scores, alignb);
    gemm_big<1, 0><<<256, 512, 0, stream>>>(
        alignb, alignb, encT, encT, 2048, 2048, 8, 4, 64,
        (size_t)2048 * 2048, (size_t)1024 * 2048, ctx, 1024, (size_t)2048 * 1024,
        nullptr, nullptr, nullptr);
  } else if (has_alignb){
    keys_gemm<<<dim3(8, 128), 256, 0, stream>>>(enc, WaTh, WaTl, bias, khi, klo);
    score_gemm<false><<<dim3(16, 16, 8), 256, 0, stream>>>(dec, nullptr, nullptr, khi, klo, scores);
    softmax_k<true><<<dim3(16384), 256, 0, stream>>>(scores, alignb);
    ctx_gemm_fast<<<dim3(1024), 256, 0, stream>>>(alignb, encT, ctx);
  } else {
    keys_gemm<<<dim3(8, 128), 256, 0, stream>>>(enc, WaTh, WaTl, bias, khi, klo);
    score_gemm<false><<<dim3(16, 16, 8), 256, 0, stream>>>(dec, nullptr, nullptr, khi, klo, scores);
    softmax_k<false><<<dim3(16384), 256, 0, stream>>>(scores, nullptr);
    if (has_encT)
      ctx_gemm<true><<<dim3(8, 16, 8), 256, 0, stream>>>(alignf, nullptr, encT, ctx);
    else
      ctx_gemm<false><<<dim3(8, 16, 8), 256, 0, stream>>>(alignf, enc, nullptr, ctx);
  }
}

// Round 9
// 495.704 us; speedup vs baseline: 7.0382x; 7.0382x over previous
//
#include <hip/hip_runtime.h>

typedef __attribute__((ext_vector_type(8))) short bf16x8;
typedef __attribute__((ext_vector_type(4))) float f32x4;
typedef __attribute__((ext_vector_type(2))) float f32x2;
typedef __attribute__((ext_vector_type(4))) unsigned int u32x4;
typedef __attribute__((ext_vector_type(2))) unsigned int u32x2;

#define DEV static __device__ __forceinline__

DEV unsigned short f2bf(float x){
  unsigned u = __float_as_uint(x);
  u += 0x7fffu + ((u >> 16) & 1u);
  return (unsigned short)(u >> 16);
}
DEV float bf2f(unsigned short b){ return __uint_as_float(((unsigned)b) << 16); }

// legacy 128-tile swizzle (8 granules per 128B row)
DEV int swz8(int row){ return (row + (row >> 3)) & 7; }
DEV int swzb(int row, int cb){ return cb ^ (swz8(row) << 4); }
DEV int loff(int row, int cb){ return row * 128 + swzb(row, cb); }

DEV f32x4 mfma16(bf16x8 a, bf16x8 b, f32x4 c){
  return __builtin_amdgcn_mfma_f32_16x16x32_bf16(a, b, c, 0, 0, 0);
}

typedef __attribute__((address_space(3))) void lds_vt;
typedef const __attribute__((address_space(1))) void gm_vt;
DEV void gload16(const void* g, void* l){
  __builtin_amdgcn_global_load_lds((gm_vt*)g, (lds_vt*)l, 16, 0, 0);
}

// ============== BIG-TILE DEEP-PIPELINED GEMM (256x256, BK=32, bf16 planes) ==============
// 512 thr / 8 waves (2x4); wave tile 128x64; M_rep=8, N_rep=4; acc = 128 AGPR.
// __launch_bounds__(512,2): 256-reg budget, NO spill (round-8 lesson: (512,4)
// spilled the accumulator -> 3.3GB scratch traffic).
// LDS 128KB: 4 buffers x (A 16KB + B 16KB); depth-3 prefetch, counted vmcnt:
//   per tile t: vmcnt(8) [stage(t) done; t+1,t+2 = 8 loads stay IN FLIGHT
//   across the barrier]; s_barrier; issue stage(t+3) into buffer retired by
//   compute(t-1) [barrier-protected; t+3 = t-1 mod 4]; 12 ds_read_b128; 32 MFMA.
// Tail: vmcnt(4) at NT-2, vmcnt(0) at NT-1.
// Staging: global_load_lds w/ inverse-swizzled global source (linear LDS dest);
// reads XOR the same granule permutation (g = lg ^ ((row>>1)&3); 2-way = free).
// NPAIR=3: virtual K*3 plane-pair sequence for the hi/lo split-3 product.
// EPI: 0 = f32 C store; 1 = +bias, split-bf16 store to oh/ol.

template<int NPAIR, int EPI>
__global__ __launch_bounds__(512, 2) void gemm_big(
    const unsigned short* __restrict__ A0p, const unsigned short* __restrict__ A1p,
    const unsigned short* __restrict__ B0p, const unsigned short* __restrict__ B1p,
    int lda, int ldb, int MBLK, int NBLK, int nkt,
    size_t a_bs, size_t b_bs,
    float* __restrict__ C, int ldc, size_t c_bs,
    const float* __restrict__ bias,
    unsigned short* __restrict__ oh, unsigned short* __restrict__ ol)
{
  __shared__ char lds[131072];
  const int tid  = threadIdx.x;
  const int w    = tid >> 6;
  const int lane = tid & 63;
  const int wr = w >> 2, wc = w & 3;
  const int lr = lane & 15, lg = lane >> 4;

  // chunked XCD swizzle (nwg % 8 == 0)
  const int nwg = gridDim.x;
  const int wg  = (blockIdx.x & 7) * (nwg >> 3) + (blockIdx.x >> 3);
  const int per = MBLK * NBLK;
  const int b   = wg / per;
  const int rr  = wg - b * per;
  const int m0  = (rr / NBLK) * 256;
  const int n0  = (rr % NBLK) * 256;

  const unsigned short* Ab0 = A0p + b * a_bs + (size_t)m0 * lda;
  const unsigned short* Ab1 = A1p + b * a_bs + (size_t)m0 * lda;
  const unsigned short* Bb0 = B0p + b * b_bs + (size_t)n0 * ldb;
  const unsigned short* Bb1 = B1p + b * b_bs + (size_t)n0 * ldb;

  const int NT = nkt * NPAIR;
  const int wu = __builtin_amdgcn_readfirstlane(w);

  f32x4 acc[8][4];
#pragma unroll
  for (int m = 0; m < 8; ++m)
#pragma unroll
    for (int n = 0; n < 4; ++n) acc[m][n] = (f32x4){0.f, 0.f, 0.f, 0.f};

  auto STAGE = [&](int t, int bufsel){
    int kp, pr;
    if (NPAIR == 3){ kp = t / 3; pr = t - kp * 3; } else { kp = t; pr = 0; }
    const unsigned short* Ap = ((NPAIR == 3) && pr == 1) ? Ab1 : Ab0;
    const unsigned short* Bp = ((NPAIR == 3) && pr == 2) ? Bb1 : Bb0;
    Ap += kp * 32; Bp += kp * 32;
    char* Abuf = lds + bufsel * 32768;
    char* Bbuf = Abuf + 16384;
#pragma unroll
    for (int j = 0; j < 2; ++j){
      int rbase = wu * 32 + j * 16;
      int row = rbase + (lane >> 2);
      int g = (lane & 3) ^ ((row >> 1) & 3);
      gload16(Ap + (size_t)row * lda + g * 8, Abuf + rbase * 64);
      gload16(Bp + (size_t)row * ldb + g * 8, Bbuf + rbase * 64);
    }
  };

  STAGE(0, 0);
  STAGE(1, 1);
  STAGE(2, 2);

  for (int t = 0; t < NT; ++t){
    if (t < NT - 2)       asm volatile("s_waitcnt vmcnt(8)" ::: "memory");
    else if (t == NT - 2) asm volatile("s_waitcnt vmcnt(4)" ::: "memory");
    else                  asm volatile("s_waitcnt vmcnt(0)" ::: "memory");
    __builtin_amdgcn_s_barrier();
    __builtin_amdgcn_sched_barrier(0);
    if (t + 3 < NT) STAGE(t + 3, (t + 3) & 3);
    __builtin_amdgcn_sched_barrier(0);

    const char* Abuf = lds + (t & 3) * 32768;
    const char* Bbuf = Abuf + 16384;
    bf16x8 afr[8], bfr[4];
#pragma unroll
    for (int n = 0; n < 4; ++n){
      int row = wc * 64 + n * 16 + lr;
      int g = lg ^ ((row >> 1) & 3);
      bfr[n] = *(const bf16x8*)(Bbuf + row * 64 + g * 16);
    }
#pragma unroll
    for (int m = 0; m < 8; ++m){
      int row = wr * 128 + m * 16 + lr;
      int g = lg ^ ((row >> 1) & 3);
      afr[m] = *(const bf16x8*)(Abuf + row * 64 + g * 16);
    }
    __builtin_amdgcn_s_setprio(1);
#pragma unroll
    for (int m = 0; m < 8; ++m)
#pragma unroll
      for (int n = 0; n < 4; ++n)
        acc[m][n] = mfma16(afr[m], bfr[n], acc[m][n]);
    __builtin_amdgcn_s_setprio(0);
  }

#pragma unroll
  for (int m = 0; m < 8; ++m){
    int grow = m0 + wr * 128 + m * 16 + lg * 4;
#pragma unroll
    for (int n = 0; n < 4; ++n){
      int gcol = n0 + wc * 64 + n * 16 + lr;
      if (EPI == 0){
#pragma unroll
        for (int j = 0; j < 4; ++j)
          C[b * c_bs + (size_t)(grow + j) * ldc + gcol] = acc[m][n][j];
      } else {
        float bv = bias[gcol];
#pragma unroll
        for (int j = 0; j < 4; ++j){
          float v = acc[m][n][j] + bv;
          unsigned short h = f2bf(v);
          size_t idx = (size_t)(grow + j) * ldc + gcol;
          oh[idx] = h;
          ol[idx] = f2bf(v - bf2f(h));
        }
      }
    }
  }
}

// ---------------- legacy staging / compute (fallback tiers) ----------------

DEV void stage_raw(char* L, const unsigned short* src, int lda, int tid){
#pragma unroll
  for (int i = 0; i < 4; ++i){
    int chunk = i * 256 + tid;
    int row = chunk >> 3;
    int c8 = (chunk & 7) << 3;
    u32x4 v = *(const u32x4*)(src + (size_t)row * lda + c8);
    *(u32x4*)(L + row * 128 + swzb(row, c8 << 1)) = v;
  }
}

DEV void stage_f32_split(char* Lhi, char* Llo, const float* src, int lda, int tid){
#pragma unroll
  for (int i = 0; i < 8; ++i){
    int chunk = i * 256 + tid;
    int row = chunk >> 4;
    int c4 = (chunk & 15) << 2;
    f32x4 v = *(const f32x4*)(src + (size_t)row * lda + c4);
    unsigned short h0 = f2bf(v[0]), h1 = f2bf(v[1]), h2 = f2bf(v[2]), h3 = f2bf(v[3]);
    u32x2 hw, lw;
    hw[0] = (unsigned)h0 | ((unsigned)h1 << 16); hw[1] = (unsigned)h2 | ((unsigned)h3 << 16);
    lw[0] = (unsigned)f2bf(v[0] - bf2f(h0)) | ((unsigned)f2bf(v[1] - bf2f(h1)) << 16);
    lw[1] = (unsigned)f2bf(v[2] - bf2f(h2)) | ((unsigned)f2bf(v[3] - bf2f(h3)) << 16);
    int off = row * 128 + swzb(row, c4 << 1);
    *(u32x2*)(Lhi + off) = hw;
    *(u32x2*)(Llo + off) = lw;
  }
}

DEV void stage_f32_plain(char* L, const float* src, int lda, int tid){
#pragma unroll
  for (int i = 0; i < 8; ++i){
    int chunk = i * 256 + tid;
    int row = chunk >> 4;
    int c4 = (chunk & 15) << 2;
    f32x4 v = *(const f32x4*)(src + (size_t)row * lda + c4);
    u32x2 hw;
    hw[0] = (unsigned)f2bf(v[0]) | ((unsigned)f2bf(v[1]) << 16);
    hw[1] = (unsigned)f2bf(v[2]) | ((unsigned)f2bf(v[3]) << 16);
    *(u32x2*)(L + row * 128 + swzb(row, c4 << 1)) = hw;
  }
}

DEV void stage_f32_T(char* L, const float* src, int ldb, int tid){
#pragma unroll
  for (int i = 0; i < 8; ++i){
    int mb = i * 256 + tid;
    int np = mb & 63, kp = mb >> 6;
    int gk = kp << 1, gn = np << 1;
    const float* p = src + (size_t)gk * ldb + gn;
    f32x2 r0 = *(const f32x2*)p;
    f32x2 r1 = *(const f32x2*)(p + ldb);
    *(unsigned*)(L + gn * 128 + swzb(gn, gk << 1))           = (unsigned)f2bf(r0[0]) | ((unsigned)f2bf(r1[0]) << 16);
    *(unsigned*)(L + (gn + 1) * 128 + swzb(gn + 1, gk << 1)) = (unsigned)f2bf(r0[1]) | ((unsigned)f2bf(r1[1]) << 16);
  }
}

DEV void compute_split(f32x4 acc[4][4], const char* Ahi, const char* Alo,
                       const char* Bhi, const char* Blo, int wr, int wc, int lane){
  int lr = lane & 15, lg = lane >> 4;
#pragma unroll
  for (int kk = 0; kk < 2; ++kk){
    int cb = kk * 64 + lg * 16;
    bf16x8 ah[4], al[4], bh[4], bl[4];
#pragma unroll
    for (int m = 0; m < 4; ++m){
      int r = wr * 64 + m * 16 + lr;
      ah[m] = *(const bf16x8*)(Ahi + loff(r, cb));
      al[m] = *(const bf16x8*)(Alo + loff(r, cb));
    }
#pragma unroll
    for (int n = 0; n < 4; ++n){
      int r = wc * 64 + n * 16 + lr;
      bh[n] = *(const bf16x8*)(Bhi + loff(r, cb));
      bl[n] = *(const bf16x8*)(Blo + loff(r, cb));
    }
#pragma unroll
    for (int m = 0; m < 4; ++m)
#pragma unroll
      for (int n = 0; n < 4; ++n){
        acc[m][n] = mfma16(ah[m], bh[n], acc[m][n]);
        acc[m][n] = mfma16(al[m], bh[n], acc[m][n]);
        acc[m][n] = mfma16(ah[m], bl[n], acc[m][n]);
      }
  }
}

DEV void compute_plain(f32x4 acc[4][4], const char* A, const char* B, int wr, int wc, int lane){
  int lr = lane & 15, lg = lane >> 4;
#pragma unroll
  for (int kk = 0; kk < 2; ++kk){
    int cb = kk * 64 + lg * 16;
    bf16x8 af[4], bf_[4];
#pragma unroll
    for (int m = 0; m < 4; ++m)
      af[m] = *(const bf16x8*)(A + loff(wr * 64 + m * 16 + lr, cb));
#pragma unroll
    for (int n = 0; n < 4; ++n)
      bf_[n] = *(const bf16x8*)(B + loff(wc * 64 + n * 16 + lr, cb));
#pragma unroll
    for (int m = 0; m < 4; ++m)
#pragma unroll
      for (int n = 0; n < 4; ++n)
        acc[m][n] = mfma16(af[m], bf_[n], acc[m][n]);
  }
}

// ---------------- prep kernels ----------------

template<bool SPLIT>
__global__ __launch_bounds__(256) void transpose_prep(
    const float* __restrict__ in, size_t in_bstride, int in_ld,
    unsigned short* __restrict__ oh, unsigned short* __restrict__ ol,
    size_t out_bstride, int out_ld)
{
  __shared__ float T[64][65];
  const int t = threadIdx.x;
  const int r0 = blockIdx.x * 64, c0 = blockIdx.y * 64;
  const float* src = in + (size_t)blockIdx.z * in_bstride;
#pragma unroll
  for (int i = 0; i < 4; ++i){
    int r = (t >> 4) + i * 16;
    int c = (t & 15) * 4;
    f32x4 v = *(const f32x4*)(src + (size_t)(r0 + r) * in_ld + c0 + c);
#pragma unroll
    for (int j = 0; j < 4; ++j) T[r][c + j] = v[j];
  }
  __syncthreads();
#pragma unroll
  for (int i = 0; i < 4; ++i){
    int c = (t >> 4) + i * 16;
    int r = (t & 15) * 4;
    float v0 = T[r][c], v1 = T[r + 1][c], v2 = T[r + 2][c], v3 = T[r + 3][c];
    unsigned short h0 = f2bf(v0), h1 = f2bf(v1), h2 = f2bf(v2), h3 = f2bf(v3);
    u32x2 hw;
    hw[0] = (unsigned)h0 | ((unsigned)h1 << 16);
    hw[1] = (unsigned)h2 | ((unsigned)h3 << 16);
    size_t off = (size_t)blockIdx.z * out_bstride + (size_t)(c0 + c) * out_ld + r0 + r;
    *(u32x2*)(oh + off) = hw;
    if (SPLIT){
      u32x2 lw;
      lw[0] = (unsigned)f2bf(v0 - bf2f(h0)) | ((unsigned)f2bf(v1 - bf2f(h1)) << 16);
      lw[1] = (unsigned)f2bf(v2 - bf2f(h2)) | ((unsigned)f2bf(v3 - bf2f(h3)) << 16);
      *(u32x2*)(ol + off) = lw;
    }
  }
}

__global__ __launch_bounds__(256) void split_prep(
    const float* __restrict__ in, unsigned short* __restrict__ oh,
    unsigned short* __restrict__ ol)
{
  size_t i = ((size_t)blockIdx.x * 256 + threadIdx.x) * 4;
  f32x4 v = *(const f32x4*)(in + i);
  unsigned short h0 = f2bf(v[0]), h1 = f2bf(v[1]), h2 = f2bf(v[2]), h3 = f2bf(v[3]);
  u32x2 hw, lw;
  hw[0] = (unsigned)h0 | ((unsigned)h1 << 16); hw[1] = (unsigned)h2 | ((unsigned)h3 << 16);
  lw[0] = (unsigned)f2bf(v[0] - bf2f(h0)) | ((unsigned)f2bf(v[1] - bf2f(h1)) << 16);
  lw[1] = (unsigned)f2bf(v[2] - bf2f(h2)) | ((unsigned)f2bf(v[3] - bf2f(h3)) << 16);
  *(u32x2*)(oh + i) = hw;
  *(u32x2*)(ol + i) = lw;
}

// ---------------- legacy kernels (fallback tiers) ----------------

__global__ __launch_bounds__(256, 2) void keys_gemm(
    const float* __restrict__ enc,
    const unsigned short* __restrict__ WaTh, const unsigned short* __restrict__ WaTl,
    const float* __restrict__ bias,
    unsigned short* __restrict__ khi, unsigned short* __restrict__ klo)
{
  __shared__ char lds[65536];
  char *Ahi = lds, *Alo = lds + 16384, *Bhi = lds + 32768, *Blo = lds + 49152;
  const int tid = threadIdx.x;
  const int lane = tid & 63, w = tid >> 6;
  const int wr = w >> 1, wc = w & 1;
  const int lr = lane & 15, lg = lane >> 4;
  const int m0 = blockIdx.y * 128;
  const int n0 = blockIdx.x * 128;

  f32x4 acc[4][4];
#pragma unroll
  for (int m = 0; m < 4; ++m)
#pragma unroll
    for (int n = 0; n < 4; ++n) acc[m][n] = (f32x4){0.f, 0.f, 0.f, 0.f};

  for (int k0 = 0; k0 < 1024; k0 += 64){
    __syncthreads();
    stage_f32_split(Ahi, Alo, enc + (size_t)m0 * 1024 + k0, 1024, tid);
    stage_raw(Bhi, WaTh + (size_t)n0 * 1024 + k0, 1024, tid);
    stage_raw(Blo, WaTl + (size_t)n0 * 1024 + k0, 1024, tid);
    __syncthreads();
    compute_split(acc, Ahi, Alo, Bhi, Blo, wr, wc, lane);
  }

#pragma unroll
  for (int n = 0; n < 4; ++n){
    int col = n0 + wc * 64 + n * 16 + lr;
    float bv = bias[col];
#pragma unroll
    for (int m = 0; m < 4; ++m){
      int rbase = m0 + wr * 64 + m * 16 + lg * 4;
#pragma unroll
      for (int j = 0; j < 4; ++j){
        float v = acc[m][n][j] + bv;
        unsigned short h = f2bf(v);
        size_t idx = (size_t)(rbase + j) * 1024 + col;
        khi[idx] = h;
        klo[idx] = f2bf(v - bf2f(h));
      }
    }
  }
}

template<bool PRESPLIT>
__global__ __launch_bounds__(256, 2) void score_gemm(
    const float* __restrict__ dec,
    const unsigned short* __restrict__ dech, const unsigned short* __restrict__ decl,
    const unsigned short* __restrict__ khi, const unsigned short* __restrict__ klo,
    float* __restrict__ scores)
{
  __shared__ char lds[65536];
  char *Ahi = lds, *Alo = lds + 16384, *Bhi = lds + 32768, *Blo = lds + 49152;
  const int tid = threadIdx.x;
  const int lane = tid & 63, w = tid >> 6;
  const int wr = w >> 1, wc = w & 1;
  const int lr = lane & 15, lg = lane >> 4;
  const int b  = blockIdx.z;
  const int m0 = blockIdx.y * 128;
  const int n0 = blockIdx.x * 128;

  f32x4 acc[4][4];
#pragma unroll
  for (int m = 0; m < 4; ++m)
#pragma unroll
    for (int n = 0; n < 4; ++n) acc[m][n] = (f32x4){0.f, 0.f, 0.f, 0.f};

  const size_t arow = (size_t)b * 2048 + m0;
  const size_t brow = (size_t)b * 2048 + n0;

  for (int k0 = 0; k0 < 1024; k0 += 64){
    __syncthreads();
    if (PRESPLIT){
      stage_raw(Ahi, dech + arow * 1024 + k0, 1024, tid);
      stage_raw(Alo, decl + arow * 1024 + k0, 1024, tid);
    } else {
      stage_f32_split(Ahi, Alo, dec + arow * 1024 + k0, 1024, tid);
    }
    stage_raw(Bhi, khi + brow * 1024 + k0, 1024, tid);
    stage_raw(Blo, klo + brow * 1024 + k0, 1024, tid);
    __syncthreads();
    compute_split(acc, Ahi, Alo, Bhi, Blo, wr, wc, lane);
  }

#pragma unroll
  for (int n = 0; n < 4; ++n){
    int col = n0 + wc * 64 + n * 16 + lr;
#pragma unroll
    for (int m = 0; m < 4; ++m){
      int rbase = m0 + wr * 64 + m * 16 + lg * 4;
#pragma unroll
      for (int j = 0; j < 4; ++j)
        scores[((size_t)b * 2048 + rbase + j) * 2048 + col] = acc[m][n][j];
    }
  }
}

// ---------------- softmax ----------------

template<bool DUALW>
__global__ __launch_bounds__(256, 4) void softmax_k(float* scores, unsigned short* alignb)
{
  const int row = blockIdx.x;
  const int t = threadIdx.x;
  float* src = scores + (size_t)row * 2048;
  f32x4 va = *(const f32x4*)(src + t * 8);
  f32x4 vb = *(const f32x4*)(src + t * 8 + 4);
  float f[8];
#pragma unroll
  for (int j = 0; j < 4; ++j){ f[j] = va[j]; f[4 + j] = vb[j]; }
  float m = -3.0e38f;
#pragma unroll
  for (int j = 0; j < 8; ++j) m = fmaxf(m, f[j]);
#pragma unroll
  for (int o = 1; o < 64; o <<= 1) m = fmaxf(m, __shfl_xor(m, o));
  __shared__ float red[4];
  const int wid = t >> 6;
  if ((t & 63) == 0) red[wid] = m;
  __syncthreads();
  m = fmaxf(fmaxf(red[0], red[1]), fmaxf(red[2], red[3]));
  float p[8]; float s = 0.f;
#pragma unroll
  for (int j = 0; j < 8; ++j){ p[j] = __expf(f[j] - m); s += p[j]; }
#pragma unroll
  for (int o = 1; o < 64; o <<= 1) s += __shfl_xor(s, o);
  __syncthreads();
  if ((t & 63) == 0) red[wid] = s;
  __syncthreads();
  s = (red[0] + red[1]) + (red[2] + red[3]);
  float inv = 1.0f / s;
  f32x4 oa, ob;
#pragma unroll
  for (int j = 0; j < 4; ++j){ oa[j] = p[j] * inv; ob[j] = p[4 + j] * inv; }
  *(f32x4*)(src + t * 8)     = oa;
  *(f32x4*)(src + t * 8 + 4) = ob;
  if (DUALW){
    u32x4 wv;
#pragma unroll
    for (int j = 0; j < 4; ++j){
      float x0 = (j < 2) ? oa[2 * j] : ob[2 * j - 4];
      float x1 = (j < 2) ? oa[2 * j + 1] : ob[2 * j - 3];
      wv[j] = (unsigned)f2bf(x0) | ((unsigned)f2bf(x1) << 16);
    }
    *(u32x4*)(alignb + (size_t)row * 2048 + t * 8) = wv;
  }
}

// ---------------- legacy ctx kernels (fallback tiers) ----------------

__global__ __launch_bounds__(256, 3) void ctx_gemm_fast(
    const unsigned short* __restrict__ alignb,
    const unsigned short* __restrict__ encT,
    float* __restrict__ ctx)
{
  __shared__ char lds[32768];
  char *A = lds, *B = lds + 16384;
  const int tid = threadIdx.x;
  const int lane = tid & 63, w = tid >> 6;
  const int wr = w >> 1, wc = w & 1;
  const int lr = lane & 15, lg = lane >> 4;
  const int wg = blockIdx.x;
  const int n0 = (wg & 7) * 128;
  const int m0 = ((wg >> 3) & 15) * 128;
  const int b  = wg >> 7;

  const unsigned short* Asrc = alignb + ((size_t)b * 2048 + m0) * 2048;
  const unsigned short* Bsrc = encT   + (size_t)b * 2097152 + (size_t)n0 * 2048;

  f32x4 acc[4][4];
#pragma unroll
  for (int m = 0; m < 4; ++m)
#pragma unroll
    for (int n = 0; n < 4; ++n) acc[m][n] = (f32x4){0.f, 0.f, 0.f, 0.f};

  const int row_ = tid >> 3;
  const int c8_  = (tid & 7) << 3;

  u32x4 ra[4], rb[4];
#pragma unroll
  for (int i = 0; i < 4; ++i){
    int row = row_ + i * 32;
    ra[i] = *(const u32x4*)(Asrc + (size_t)row * 2048 + c8_);
    rb[i] = *(const u32x4*)(Bsrc + (size_t)row * 2048 + c8_);
  }

  for (int t = 0; t < 32; ++t){
    __syncthreads();
#pragma unroll
    for (int i = 0; i < 4; ++i){
      int row = row_ + i * 32;
      int off = row * 128 + swzb(row, c8_ << 1);
      *(u32x4*)(A + off) = ra[i];
      *(u32x4*)(B + off) = rb[i];
    }
    __syncthreads();
    if (t + 1 < 32){
      int k0 = (t + 1) * 64;
#pragma unroll
      for (int i = 0; i < 4; ++i){
        int row = row_ + i * 32;
        ra[i] = *(const u32x4*)(Asrc + (size_t)row * 2048 + k0 + c8_);
        rb[i] = *(const u32x4*)(Bsrc + (size_t)row * 2048 + k0 + c8_);
      }
    }
    compute_plain(acc, A, B, wr, wc, lane);
  }

#pragma unroll
  for (int n = 0; n < 4; ++n){
    int col = n0 + wc * 64 + n * 16 + lr;
#pragma unroll
    for (int m = 0; m < 4; ++m){
      int rbase = m0 + wr * 64 + m * 16 + lg * 4;
#pragma unroll
      for (int j = 0; j < 4; ++j)
        ctx[((size_t)b * 2048 + rbase + j) * 1024 + col] = acc[m][n][j];
    }
  }
}

template<bool TRANS_WS>
__global__ __launch_bounds__(256, 2) void ctx_gemm(
    const float* __restrict__ alignf,
    const float* __restrict__ enc, const unsigned short* __restrict__ encT,
    float* __restrict__ ctx)
{
  __shared__ char lds[32768];
  char *A = lds, *B = lds + 16384;
  const int tid = threadIdx.x;
  const int lane = tid & 63, w = tid >> 6;
  const int wr = w >> 1, wc = w & 1;
  const int lr = lane & 15, lg = lane >> 4;
  const int b  = blockIdx.z;
  const int m0 = blockIdx.y * 128;
  const int n0 = blockIdx.x * 128;

  f32x4 acc[4][4];
#pragma unroll
  for (int m = 0; m < 4; ++m)
#pragma unroll
    for (int n = 0; n < 4; ++n) acc[m][n] = (f32x4){0.f, 0.f, 0.f, 0.f};

  const float* Asrc = alignf + ((size_t)b * 2048 + m0) * 2048;

  for (int k0 = 0; k0 < 2048; k0 += 64){
    __syncthreads();
    stage_f32_plain(A, Asrc + k0, 2048, tid);
    if (TRANS_WS)
      stage_raw(B, encT + (size_t)b * 2097152 + (size_t)n0 * 2048 + k0, 2048, tid);
    else
      stage_f32_T(B, enc + ((size_t)b * 2048 + k0) * 1024 + n0, 1024, tid);
    __syncthreads();
    compute_plain(acc, A, B, wr, wc, lane);
  }

#pragma unroll
  for (int n = 0; n < 4; ++n){
    int col = n0 + wc * 64 + n * 16 + lr;
#pragma unroll
    for (int m = 0; m < 4; ++m){
      int rbase = m0 + wr * 64 + m * 16 + lg * 4;
#pragma unroll
      for (int j = 0; j < 4; ++j)
        ctx[((size_t)b * 2048 + rbase + j) * 1024 + col] = acc[m][n][j];
    }
  }
}

// ---------------- launch ----------------
// d_out (f32): ctx [8,2048,1024] | align [8,2048,2048].
// keys bf16 hi/lo planes in ctx region (67 MB, overwritten last).
// Wa^T planes in align tail (4 MB). enc hi/lo planes in align head (67 MB) —
// consumed by keys stage, then overwritten by score output (stream order).
// d_ws tiers: >=33.5 MB encT | >=100.7 MB +alignb | >=167.8 MB +dec planes.

extern "C" void kernel_launch(void* const* d_in, const int* in_sizes, int n_in,
                              void* d_out, int out_size, void* d_ws, size_t ws_size,
                              hipStream_t stream) {
  const float* enc  = (const float*)d_in[0];
  const float* dec  = (const float*)d_in[1];
  const float* Wa   = (const float*)d_in[2];
  const float* bias = (const float*)d_in[3];

  float* out    = (float*)d_out;
  float* ctx    = out;
  float* alignf = out + (size_t)8 * 2048 * 1024;
  float* scores = alignf;

  unsigned short* khi = (unsigned short*)ctx;
  unsigned short* klo = khi + (size_t)16384 * 1024;

  unsigned short* WaTh = (unsigned short*)(alignf + 32505856);
  unsigned short* WaTl = WaTh + (size_t)1024 * 1024;

  unsigned short* ench = (unsigned short*)alignf;
  unsigned short* encl = ench + (size_t)16384 * 1024;

  const size_t ENCT_B   = (size_t)8 * 1024 * 2048 * 2;
  const size_t ALIGNB_B = (size_t)8 * 2048 * 2048 * 2;
  const size_t DECP_B   = (size_t)8 * 2048 * 1024 * 2;
  bool has_encT   = ws_size >= ENCT_B;
  bool has_alignb = ws_size >= ENCT_B + ALIGNB_B;
  bool has_decp   = ws_size >= ENCT_B + ALIGNB_B + 2 * DECP_B;
  unsigned short* encT   = (unsigned short*)d_ws;
  unsigned short* alignb = (unsigned short*)((char*)d_ws + ENCT_B);
  unsigned short* dech   = (unsigned short*)((char*)d_ws + ENCT_B + ALIGNB_B);
  unsigned short* decl   = (unsigned short*)((char*)d_ws + ENCT_B + ALIGNB_B + DECP_B);

  transpose_prep<true><<<dim3(16, 16, 1), 256, 0, stream>>>(
      Wa, 0, 1024, WaTh, WaTl, 0, 1024);
  if (has_encT)
    transpose_prep<false><<<dim3(32, 16, 8), 256, 0, stream>>>(
        enc, (size_t)2048 * 1024, 1024, encT, nullptr, (size_t)1024 * 2048, 2048);
  if (has_decp)
    split_prep<<<dim3(16384), 256, 0, stream>>>(dec, dech, decl);

  if (has_decp){
    split_prep<<<dim3(16384), 256, 0, stream>>>(enc, ench, encl);
    gemm_big<3, 1><<<256, 512, 0, stream>>>(
        ench, encl, WaTh, WaTl, 1024, 1024, 64, 4, 32,
        0, 0, nullptr, 1024, 0, bias, khi, klo);
    gemm_big<3, 0><<<512, 512, 0, stream>>>(
        dech, decl, khi, klo, 1024, 1024, 8, 8, 32,
        (size_t)2048 * 1024, (size_t)2048 * 1024, scores, 2048, (size_t)2048 * 2048,
        nullptr, nullptr, nullptr);
    softmax_k<true><<<dim3(16384), 256, 0, stream>>>(scores, alignb);
    gemm_big<1, 0><<<256, 512, 0, stream>>>(
        alignb, alignb, encT, encT, 2048, 2048, 8, 4, 64,
        (size_t)2048 * 2048, (size_t)1024 * 2048, ctx, 1024, (size_t)2048 * 1024,
        nullptr, nullptr, nullptr);
  } else if (has_alignb){
    keys_gemm<<<dim3(8, 128), 256, 0, stream>>>(enc, WaTh, WaTl, bias, khi, klo);
    score_gemm<false><<<dim3(16, 16, 8), 256, 0, stream>>>(dec, nullptr, nullptr, khi, klo, scores);
    softmax_k<true><<<dim3(16384), 256, 0, stream>>>(scores, alignb);
    ctx_gemm_fast<<<dim3(1024), 256, 0, stream>>>(alignb, encT, ctx);
  } else {
    keys_gemm<<<dim3(8, 128), 256, 0, stream>>>(enc, WaTh, WaTl, bias, khi, klo);
    score_gemm<false><<<dim3(16, 16, 8), 256, 0, stream>>>(dec, nullptr, nullptr, khi, klo, scores);
    softmax_k<false><<<dim3(16384), 256, 0, stream>>>(scores, nullptr);
    if (has_encT)
      ctx_gemm<true><<<dim3(8, 16, 8), 256, 0, stream>>>(alignf, nullptr, encT, ctx);
    else
      ctx_gemm<false><<<dim3(8, 16, 8), 256, 0, stream>>>(alignf, enc, nullptr, ctx);
  }
}